// Round 1
// 384.974 us; speedup vs baseline: 1.0822x; 1.0822x over previous
//
#include <hip/hip_runtime.h>

// Problem constants (all fp32 in global memory — verified round 2)
#define BS    8
#define CDIM  4096
#define TDIM  512
#define NH    8
#define HD    64
#define NDIM  512
#define INV_SCALE 0.044194173824159216f   // 1/sqrt(512)

typedef __bf16 bf16x8 __attribute__((ext_vector_type(8)));
typedef float  f32x4  __attribute__((ext_vector_type(4)));

static __device__ __forceinline__ unsigned short f2b(float f) {
    union { float f; unsigned int i; } x; x.f = f;
    unsigned int r = x.i + 0x7FFFu + ((x.i >> 16) & 1u);   // RNE
    return (unsigned short)(r >> 16);
}

static __device__ __forceinline__ void gl2lds16(const unsigned short* g,
                                                unsigned short* l) {
    __builtin_amdgcn_global_load_lds(
        (const __attribute__((address_space(1))) void*)g,
        (__attribute__((address_space(3))) void*)l, 16, 0, 0);
}

// ---------------------------------------------------------------------------
// Transpose+convert: x[b][c][t] fp32 -> xT[b][t][c] bf16.  64x64 tiles.
// grid (CDIM/64, TDIM/64, 16): z>>3 selects q/k, b = z&7. block 256.
// LDS stride 65 shorts -> both scalar phases conflict-free (addr%64 unique).
// ---------------------------------------------------------------------------
__global__ __launch_bounds__(256) void transpose_qk_kernel(
    const float* __restrict__ q, const float* __restrict__ k,
    unsigned short* __restrict__ qT, unsigned short* __restrict__ kT)
{
    __shared__ unsigned short Ls[64 * 65];

    const int z = blockIdx.z;
    const int b = z & 7;
    const float* src = (z >> 3) ? k : q;
    unsigned short* dst = (z >> 3) ? kT : qT;

    const int c0 = blockIdx.x * 64;
    const int t0 = blockIdx.y * 64;
    const int tid = threadIdx.x;

    // load: row r (c-local) = tid>>2, 16 floats at t-seg (tid&3)*16
    {
        const int r = tid >> 2, seg = (tid & 3) * 16;
        const float* p = src + ((size_t)b * CDIM + c0 + r) * TDIM + t0 + seg;
        float4 f0 = *(const float4*)p, f1 = *(const float4*)(p + 4);
        float4 f2 = *(const float4*)(p + 8), f3 = *(const float4*)(p + 12);
        float ff[16] = {f0.x, f0.y, f0.z, f0.w, f1.x, f1.y, f1.z, f1.w,
                        f2.x, f2.y, f2.z, f2.w, f3.x, f3.y, f3.z, f3.w};
#pragma unroll
        for (int j = 0; j < 16; j++) Ls[(seg + j) * 65 + r] = f2b(ff[j]);
    }
    __syncthreads();
    // store: row t' = tid>>2, 16 shorts at c-seg (tid&3)*16
    {
        const int tp = tid >> 2, cs = (tid & 3) * 16;
        alignas(16) unsigned short u[16];
#pragma unroll
        for (int j = 0; j < 16; j++) u[j] = Ls[tp * 65 + cs + j];
        unsigned short* o = dst + ((size_t)b * TDIM + t0 + tp) * CDIM + c0 + cs;
        *(float4*)o = *(const float4*)u;
        *(float4*)(o + 8) = *(const float4*)(u + 8);
    }
}

// ---------------------------------------------------------------------------
// Elementwise fp32 -> bf16 (n must be multiple of 8; one thread = 8 elems)
// ---------------------------------------------------------------------------
__global__ __launch_bounds__(256) void cvt_kernel(
    const float* __restrict__ in, unsigned short* __restrict__ out, int n8)
{
    int i = blockIdx.x * 256 + threadIdx.x;
    if (i >= n8) return;
    float4 f0 = ((const float4*)in)[i * 2], f1 = ((const float4*)in)[i * 2 + 1];
    alignas(16) unsigned short t[8] = {f2b(f0.x), f2b(f0.y), f2b(f0.z), f2b(f0.w),
                                       f2b(f1.x), f2b(f1.y), f2b(f1.z), f2b(f1.w)};
    ((float4*)out)[i] = *(const float4*)t;
}

// ---------------------------------------------------------------------------
// m97-style 128x128 GEMM: C[m][n] = sum_k A[m][k] * B[n][k].
// B always bf16 via global_load_lds(16B). A: bf16 DMA path, or fp32
// VGPR-staged (a_f32, block-uniform). ldk = row stride of A and B.
// grid (M/128, N/128, batches*(kmask+1)). Tiles: BK=32, 4 waves -> 64x64 each.
// Split-K: z = (b << zshift) | ks; block covers K rows [ks*K, (ks+1)*K);
// C written at offC = b*sCb + ks*sCsplit (fp32 partials when split).
// ---------------------------------------------------------------------------
__global__ __launch_bounds__(256) void gemm128_kernel(
    const void* __restrict__ Av, int a_f32, size_t sAb,
    const unsigned short* __restrict__ B, size_t sBb,
    void* __restrict__ Cv, int c_f32, int writeT, int ldc, size_t sCb,
    int ldk, int K, int zshift, int zmask, size_t sCsplit)
{
    __shared__ unsigned short As[128 * 32];
    __shared__ unsigned short Bs[128 * 32];

    const int tid  = threadIdx.x;
    const int wave = tid >> 6, lane = tid & 63;
    const int quad = lane >> 4, l16 = lane & 15;
    const int wm = wave >> 1, wn = wave & 1;
    const int m0 = blockIdx.x * 128, n0 = blockIdx.y * 128;
    const int z = blockIdx.z;
    const int b = z >> zshift;
    const int ks = z & zmask;
    const int kbase = ks * K;

    const unsigned short* Bb = B + (size_t)b * sBb;

    f32x4 acc[4][4];
#pragma unroll
    for (int i = 0; i < 4; i++)
#pragma unroll
        for (int j = 0; j < 4; j++) acc[i][j] = (f32x4){0.f, 0.f, 0.f, 0.f};

    const int ldr = lane >> 2, ldc8 = (lane & 3) * 8;  // DMA row/col within panel
    const int ar = tid >> 1, as0 = (tid & 1) * 16;     // fp32-stage row/seg

    for (int k0 = kbase; k0 < kbase + K; k0 += 32) {
        __syncthreads();
        if (a_f32) {
            const float* Ab = (const float*)Av + (size_t)b * sAb +
                              (size_t)(m0 + ar) * ldk + k0 + as0;
            float4 f0 = *(const float4*)Ab,       f1 = *(const float4*)(Ab + 4);
            float4 f2 = *(const float4*)(Ab + 8), f3 = *(const float4*)(Ab + 12);
            alignas(16) unsigned short t16[16] = {
                f2b(f0.x), f2b(f0.y), f2b(f0.z), f2b(f0.w),
                f2b(f1.x), f2b(f1.y), f2b(f1.z), f2b(f1.w),
                f2b(f2.x), f2b(f2.y), f2b(f2.z), f2b(f2.w),
                f2b(f3.x), f2b(f3.y), f2b(f3.z), f2b(f3.w)};
            *(float4*)&As[ar * 32 + as0]     = ((const float4*)t16)[0];
            *(float4*)&As[ar * 32 + as0 + 8] = ((const float4*)t16)[1];
        } else {
            const unsigned short* Ab = (const unsigned short*)Av + (size_t)b * sAb;
#pragma unroll
            for (int i = 0; i < 2; i++) {
                int panel = wave * 2 + i;  // 16-row panel
                gl2lds16(&Ab[(size_t)(m0 + panel * 16 + ldr) * ldk + k0 + ldc8],
                         &As[panel * 512]);
            }
        }
#pragma unroll
        for (int i = 0; i < 2; i++) {
            int panel = wave * 2 + i;
            gl2lds16(&Bb[(size_t)(n0 + panel * 16 + ldr) * ldk + k0 + ldc8],
                     &Bs[panel * 512]);
        }
        __syncthreads();

        bf16x8 af[4], bf[4];
#pragma unroll
        for (int i = 0; i < 4; i++) {
            af[i] = *(const bf16x8*)&As[(wm * 64 + i * 16 + l16) * 32 + quad * 8];
            bf[i] = *(const bf16x8*)&Bs[(wn * 64 + i * 16 + l16) * 32 + quad * 8];
        }
#pragma unroll
        for (int mb = 0; mb < 4; mb++)
#pragma unroll
            for (int nb = 0; nb < 4; nb++)
                acc[mb][nb] = __builtin_amdgcn_mfma_f32_16x16x32_bf16(
                    af[mb], bf[nb], acc[mb][nb], 0, 0, 0);
    }

    const size_t offC = (size_t)b * sCb + (size_t)ks * sCsplit;
#pragma unroll
    for (int mb = 0; mb < 4; mb++)
#pragma unroll
        for (int nb = 0; nb < 4; nb++)
#pragma unroll
            for (int r = 0; r < 4; r++) {
                int row = m0 + wm * 64 + mb * 16 + quad * 4 + r;
                int col = n0 + wn * 64 + nb * 16 + l16;
                size_t idx = offC + (writeT ? (size_t)col * ldc + row
                                            : (size_t)row * ldc + col);
                if (c_f32) ((float*)Cv)[idx] = acc[mb][nb][r];
                else ((unsigned short*)Cv)[idx] = f2b(acc[mb][nb][r]);
            }
}

// ---------------------------------------------------------------------------
// Sum 4 fp32 split-K partials (each 2,097,152 floats) -> bf16 G.
// 1024 blocks x 256 threads, 8 floats per thread.
// ---------------------------------------------------------------------------
__global__ __launch_bounds__(256) void reduceG_kernel(
    const float* __restrict__ P, unsigned short* __restrict__ G)
{
    const int i = blockIdx.x * 256 + threadIdx.x;   // 8 floats each
    const float4* p = (const float4*)P + (size_t)i * 2;
    const size_t st = 2097152 / 4;                  // float4 stride per split
    float4 a0 = p[0], a1 = p[1];
#pragma unroll
    for (int s = 1; s < 4; s++) {
        float4 b0 = p[(size_t)s * st], b1 = p[(size_t)s * st + 1];
        a0.x += b0.x; a0.y += b0.y; a0.z += b0.z; a0.w += b0.w;
        a1.x += b1.x; a1.y += b1.y; a1.z += b1.z; a1.w += b1.w;
    }
    alignas(16) unsigned short t[8] = {f2b(a0.x), f2b(a0.y), f2b(a0.z), f2b(a0.w),
                                       f2b(a1.x), f2b(a1.y), f2b(a1.z), f2b(a1.w)};
    ((float4*)G)[i] = *(const float4*)t;
}

// ---------------------------------------------------------------------------
// 64x64 dtype-flex GEMM (round-3, verified) for small shapes.
// ---------------------------------------------------------------------------
__global__ __launch_bounds__(256) void gemm64_kernel(
    const void* __restrict__ Av, int a_f32, size_t sAb, size_t sAh,
    const unsigned short* __restrict__ B, size_t sBb, size_t sBh,
    void* __restrict__ Cv, int c_f32, int writeT, int ldc, size_t sCb, size_t sCh,
    int K, int hshift, int hmask)
{
    __shared__ unsigned short As[64][40];
    __shared__ unsigned short Bs[64][40];

    const int tid  = threadIdx.x;
    const int wave = tid >> 6, lane = tid & 63;
    const int quad = lane >> 4, l16 = lane & 15;
    const int m0 = blockIdx.x * 64, n0 = blockIdx.y * 64;
    const int bz = blockIdx.z;
    const int b = bz >> hshift, h = bz & hmask;

    f32x4 acc[4];
#pragma unroll
    for (int i = 0; i < 4; i++) acc[i] = (f32x4){0.f, 0.f, 0.f, 0.f};

    const int ldrow = tid >> 2, ldseg = (tid & 3) * 8;
    const size_t offA = (size_t)b * sAb + (size_t)h * sAh;
    const size_t offB = (size_t)b * sBb + (size_t)h * sBh;

    for (int k0 = 0; k0 < K; k0 += 32) {
        __syncthreads();
        if (a_f32) {
            const float* p = (const float*)Av + offA + (size_t)(m0 + ldrow) * K + k0 + ldseg;
            float4 lo = *(const float4*)p, hi = *(const float4*)(p + 4);
            alignas(16) unsigned short t8[8] = {
                f2b(lo.x), f2b(lo.y), f2b(lo.z), f2b(lo.w),
                f2b(hi.x), f2b(hi.y), f2b(hi.z), f2b(hi.w)};
            *(float4*)&As[ldrow][ldseg] = *(const float4*)t8;
        } else {
            const unsigned short* p = (const unsigned short*)Av + offA +
                                      (size_t)(m0 + ldrow) * K + k0 + ldseg;
            *(float4*)&As[ldrow][ldseg] = *(const float4*)p;
        }
        {
            const unsigned short* p = B + offB + (size_t)(n0 + ldrow) * K + k0 + ldseg;
            *(float4*)&Bs[ldrow][ldseg] = *(const float4*)p;
        }
        __syncthreads();

        bf16x8 a = *(const bf16x8*)&As[wave * 16 + l16][quad * 8];
#pragma unroll
        for (int nb = 0; nb < 4; nb++) {
            bf16x8 bb = *(const bf16x8*)&Bs[nb * 16 + l16][quad * 8];
            acc[nb] = __builtin_amdgcn_mfma_f32_16x16x32_bf16(a, bb, acc[nb], 0, 0, 0);
        }
    }

    const size_t offC = (size_t)b * sCb + (size_t)h * sCh;
#pragma unroll
    for (int nb = 0; nb < 4; nb++)
#pragma unroll
        for (int r = 0; r < 4; r++) {
            int row = m0 + wave * 16 + quad * 4 + r;
            int col = n0 + nb * 16 + l16;
            size_t idx = offC + (writeT ? (size_t)col * ldc + row
                                        : (size_t)row * ldc + col);
            if (c_f32) ((float*)Cv)[idx] = acc[nb][r];
            else ((unsigned short*)Cv)[idx] = f2b(acc[nb][r]);
        }
}

// ---------------------------------------------------------------------------
// WvT[h][t][e] = bf16(Wv[h][e][t])
// ---------------------------------------------------------------------------
__global__ __launch_bounds__(256) void transpose_wv_kernel(
    const float* __restrict__ Wv, unsigned short* __restrict__ WvT)
{
    int i = blockIdx.x * 256 + threadIdx.x;
    int h = i >> 15, r = i & 32767;
    int t = r >> 6, e = i & 63;
    WvT[i] = f2b(Wv[(size_t)h * 32768 + (size_t)e * 512 + t]);
}

// ---------------------------------------------------------------------------
__global__ __launch_bounds__(64) void softmax_kernel(
    const float* __restrict__ S, unsigned short* __restrict__ w)
{
    const int bh = blockIdx.x;
    const int d  = threadIdx.x;
    const float* s = S + (size_t)bh * (HD * HD) + d * HD;
    float v[64];
    float m = -1e30f;
#pragma unroll
    for (int e = 0; e < 64; e++) { v[e] = s[e] * INV_SCALE; m = fmaxf(m, v[e]); }
    float sum = 0.f;
#pragma unroll
    for (int e = 0; e < 64; e++) { v[e] = __expf(v[e] - m); sum += v[e]; }
    float rinv = 1.0f / sum;
    unsigned short* o = w + (size_t)bh * (HD * HD) + d * HD;
#pragma unroll
    for (int e = 0; e < 64; e++) o[e] = f2b(v[e] * rinv);
}

// ---------------------------------------------------------------------------
extern "C" void kernel_launch(void* const* d_in, const int* in_sizes, int n_in,
                              void* d_out, int out_size, void* d_ws, size_t ws_size,
                              hipStream_t stream)
{
    const float* q  = (const float*)d_in[0];
    const float* k  = (const float*)d_in[1];
    const float* v  = (const float*)d_in[2];
    const float* Wq = (const float*)d_in[3];
    const float* Wk = (const float*)d_in[4];
    const float* Wv = (const float*)d_in[5];
    const float* Wo = (const float*)d_in[6];

    // workspace (element counts). Peak concurrent use:
    //   qT(32MB) + kT(32MB) + G(4MB) + P(32MB, aliases tmpT..free tail) = 100MB
    //   <= 102.7MB proven in round 2. P is dead after reduceG; tmpT/WkB/WoB/
    //   WvT/w/WveT/W2/S are all written after that point (single stream).
    unsigned short* qT   = (unsigned short*)d_ws;        // 16,777,216
    unsigned short* kT   = qT + 16777216;                // 16,777,216
    unsigned short* G    = kT + 16777216;                // 2,097,152
    unsigned short* tmpT = G + 2097152;                  // 2,097,152
    unsigned short* WkB  = tmpT + 2097152;               // 262,144
    unsigned short* WoB  = WkB + 262144;                 // 262,144
    unsigned short* WvT  = WoB + 262144;                 // 262,144
    unsigned short* w    = WvT + 262144;                 // 262,144
    unsigned short* WveT = w + 262144;                   // 2,097,152
    unsigned short* W2   = WveT + 2097152;               // 2,097,152
    float*          S    = (float*)(W2 + 2097152);       // 262,144 fp32
    float*          P    = (float*)tmpT;                 // 8,388,608 fp32 (split-K partials)

    // 0. q,k -> qT,kT (bf16, [b][t][c])
    transpose_qk_kernel<<<dim3(64, 8, 16), 256, 0, stream>>>(q, k, qT, kT);

    // 1. G[b][t][s] = sum_c qT[b][t][c] kT[b][s][c]   (K=4096, split-K x4)
    //    z = b*4 + ks; each block does K=1024 -> 512 blocks (2/CU).
    gemm128_kernel<<<dim3(4, 4, BS * 4), 256, 0, stream>>>(
        qT, 0, 16777216 / 8, kT, 2097152,
        P, 1, 0, 512, 262144, 4096, 1024, 2, 3, 2097152);
    reduceG_kernel<<<1024, 256, 0, stream>>>(P, G);

    // 0b. weight converts (after reduceG: their buffers alias P)
    cvt_kernel<<<128, 256, 0, stream>>>(Wk, WkB, 32768);
    cvt_kernel<<<128, 256, 0, stream>>>(Wo, WoB, 32768);
    transpose_wv_kernel<<<1024, 256, 0, stream>>>(Wv, WvT);

    // 2a. tmpT[b][he][t] = (G[b] * WkB^T)^T   (M=512 t, N=512 he, K=512 s)
    gemm128_kernel<<<dim3(4, 4, BS), 256, 0, stream>>>(
        G, 0, 262144, WkB, 0,
        tmpT, 0, 1, 512, 262144, 512, 512, 0, 0, 0);

    // 2b. S[b,h][d][e] = Wq[h] * tmpT[b,h]^T  (M=64, N=64, K=512)
    gemm64_kernel<<<dim3(1, 1, 64), 256, 0, stream>>>(
        Wq, 1, 0, 32768, tmpT, 262144, 32768,
        S, 1, 0, 64, 32768, 4096, 512, 3, 7);

    // 3. softmax
    softmax_kernel<<<64, 64, 0, stream>>>(S, w);

    // 4. WveT[b][t][h*64+d] = (w[b,h] * WvT[h]^T)^T   (M=64, N=512, K=64)
    gemm64_kernel<<<dim3(1, 8, 64), 256, 0, stream>>>(
        w, 0, 32768, 4096, WvT, 0, 32768,
        WveT, 0, 1, 512, 262144, 64, 64, 3, 7);

    // 5. W2[b][o][t] = WoB * WveT[b]^T   (M=512, N=512, K=512)
    gemm128_kernel<<<dim3(4, 4, BS), 256, 0, stream>>>(
        WoB, 0, 0, WveT, 262144,
        W2, 0, 0, 512, 262144, 512, 512, 0, 0, 0);

    // 6. out[b][c][o] = v[b] * W2[b]^T   (M=4096, N=512, K=512, A fp32)
    gemm128_kernel<<<dim3(32, 4, BS), 256, 0, stream>>>(
        v, 1, 2097152, W2, 262144,
        d_out, 1, 0, 512, 2097152, 512, 512, 0, 0, 0);
}

// Round 2
// 383.067 us; speedup vs baseline: 1.0876x; 1.0050x over previous
//
#include <hip/hip_runtime.h>

// Problem constants (all fp32 in global memory — verified round 2)
#define BS    8
#define CDIM  4096
#define TDIM  512
#define NH    8
#define HD    64
#define NDIM  512
#define INV_SCALE 0.044194173824159216f   // 1/sqrt(512)

typedef __bf16 bf16x8 __attribute__((ext_vector_type(8)));
typedef float  f32x4  __attribute__((ext_vector_type(4)));

static __device__ __forceinline__ unsigned short f2b(float f) {
    union { float f; unsigned int i; } x; x.f = f;
    unsigned int r = x.i + 0x7FFFu + ((x.i >> 16) & 1u);   // RNE
    return (unsigned short)(r >> 16);
}

static __device__ __forceinline__ void gl2lds16(const unsigned short* g,
                                                unsigned short* l) {
    __builtin_amdgcn_global_load_lds(
        (const __attribute__((address_space(1))) void*)g,
        (__attribute__((address_space(3))) void*)l, 16, 0, 0);
}

// One counted-drain barrier per K-tile (2-phase pipeline). The asm memory
// clobbers on BOTH sides of s_barrier stop the compiler from hoisting the
// next tile's ds_reads above the barrier (cross-wave LDS visibility).
#define PIPE_BARRIER() do {                                          \
    asm volatile("s_waitcnt vmcnt(0) lgkmcnt(0)" ::: "memory");      \
    __builtin_amdgcn_s_barrier();                                    \
    asm volatile("" ::: "memory");                                   \
} while (0)

// ---------------------------------------------------------------------------
// Transpose+convert: x[b][c][t] fp32 -> xT[b][t][c] bf16.  64x64 tiles.
// grid (CDIM/64, TDIM/64, 16): z>>3 selects q/k, b = z&7. block 256.
// LDS stride 65 shorts -> both scalar phases conflict-free (addr%64 unique).
// ---------------------------------------------------------------------------
__global__ __launch_bounds__(256) void transpose_qk_kernel(
    const float* __restrict__ q, const float* __restrict__ k,
    unsigned short* __restrict__ qT, unsigned short* __restrict__ kT)
{
    __shared__ unsigned short Ls[64 * 65];

    const int z = blockIdx.z;
    const int b = z & 7;
    const float* src = (z >> 3) ? k : q;
    unsigned short* dst = (z >> 3) ? kT : qT;

    const int c0 = blockIdx.x * 64;
    const int t0 = blockIdx.y * 64;
    const int tid = threadIdx.x;

    // load: row r (c-local) = tid>>2, 16 floats at t-seg (tid&3)*16
    {
        const int r = tid >> 2, seg = (tid & 3) * 16;
        const float* p = src + ((size_t)b * CDIM + c0 + r) * TDIM + t0 + seg;
        float4 f0 = *(const float4*)p, f1 = *(const float4*)(p + 4);
        float4 f2 = *(const float4*)(p + 8), f3 = *(const float4*)(p + 12);
        float ff[16] = {f0.x, f0.y, f0.z, f0.w, f1.x, f1.y, f1.z, f1.w,
                        f2.x, f2.y, f2.z, f2.w, f3.x, f3.y, f3.z, f3.w};
#pragma unroll
        for (int j = 0; j < 16; j++) Ls[(seg + j) * 65 + r] = f2b(ff[j]);
    }
    __syncthreads();
    // store: row t' = tid>>2, 16 shorts at c-seg (tid&3)*16
    {
        const int tp = tid >> 2, cs = (tid & 3) * 16;
        alignas(16) unsigned short u[16];
#pragma unroll
        for (int j = 0; j < 16; j++) u[j] = Ls[tp * 65 + cs + j];
        unsigned short* o = dst + ((size_t)b * TDIM + t0 + tp) * CDIM + c0 + cs;
        *(float4*)o = *(const float4*)u;
        *(float4*)(o + 8) = *(const float4*)(u + 8);
    }
}

// ---------------------------------------------------------------------------
// Elementwise fp32 -> bf16 (n must be multiple of 8; one thread = 8 elems)
// ---------------------------------------------------------------------------
__global__ __launch_bounds__(256) void cvt_kernel(
    const float* __restrict__ in, unsigned short* __restrict__ out, int n8)
{
    int i = blockIdx.x * 256 + threadIdx.x;
    if (i >= n8) return;
    float4 f0 = ((const float4*)in)[i * 2], f1 = ((const float4*)in)[i * 2 + 1];
    alignas(16) unsigned short t[8] = {f2b(f0.x), f2b(f0.y), f2b(f0.z), f2b(f0.w),
                                       f2b(f1.x), f2b(f1.y), f2b(f1.z), f2b(f1.w)};
    ((float4*)out)[i] = *(const float4*)t;
}

// ---------------------------------------------------------------------------
// m97-style 128x128 GEMM, 2-phase double-buffered (T3 minimum recipe):
// C[m][n] = sum_k A[m][k] * B[n][k].
// B always bf16 via global_load_lds(16B). A: bf16 DMA path, or fp32
// VGPR-staged (a_f32, issue-early/write-late). ldk = row stride of A and B.
// grid (M/128, N/128, batches*(zmask+1)). Tiles: BK=32, 4 waves -> 64x64 each.
// Split-K: z = (b << zshift) | ks; block covers K rows [ks*K, (ks+1)*K);
// C written at offC = b*sCb + ks*sCsplit (fp32 partials when split).
// Pipeline: issue stage(t+1) -> ds_read/MFMA on tile t -> (fp32: cvt+ds_write
// t+1) -> single vmcnt(0)+lgkmcnt(0)+s_barrier per tile.
// ---------------------------------------------------------------------------
__global__ __launch_bounds__(256) void gemm128_kernel(
    const void* __restrict__ Av, int a_f32, size_t sAb,
    const unsigned short* __restrict__ B, size_t sBb,
    void* __restrict__ Cv, int c_f32, int writeT, int ldc, size_t sCb,
    int ldk, int K, int zshift, int zmask, size_t sCsplit)
{
    __shared__ unsigned short As[2][128 * 32];
    __shared__ unsigned short Bs[2][128 * 32];

    const int tid  = threadIdx.x;
    const int wave = tid >> 6, lane = tid & 63;
    const int quad = lane >> 4, l16 = lane & 15;
    const int wm = wave >> 1, wn = wave & 1;
    const int m0 = blockIdx.x * 128, n0 = blockIdx.y * 128;
    const int z = blockIdx.z;
    const int b = z >> zshift;
    const int ks = z & zmask;
    const int kbase = ks * K;

    const unsigned short* Bb   = B + (size_t)b * sBb;
    const unsigned short* Ab16 = (const unsigned short*)Av + (size_t)b * sAb;
    const float*          Ab32 = (const float*)Av + (size_t)b * sAb;

    f32x4 acc[4][4];
#pragma unroll
    for (int i = 0; i < 4; i++)
#pragma unroll
        for (int j = 0; j < 4; j++) acc[i][j] = (f32x4){0.f, 0.f, 0.f, 0.f};

    const int ldr = lane >> 2, ldc8 = (lane & 3) * 8;  // DMA row/col within panel
    const int ar = tid >> 1, as0 = (tid & 1) * 16;     // fp32-stage row/seg

    const int nt = K / 32;

    // ---- prologue: stage tile 0 into buffer 0
    if (a_f32) {
        const float* p = Ab32 + (size_t)(m0 + ar) * ldk + kbase + as0;
        float4 f0 = *(const float4*)p,       f1 = *(const float4*)(p + 4);
        float4 f2 = *(const float4*)(p + 8), f3 = *(const float4*)(p + 12);
        alignas(16) unsigned short t16[16] = {
            f2b(f0.x), f2b(f0.y), f2b(f0.z), f2b(f0.w),
            f2b(f1.x), f2b(f1.y), f2b(f1.z), f2b(f1.w),
            f2b(f2.x), f2b(f2.y), f2b(f2.z), f2b(f2.w),
            f2b(f3.x), f2b(f3.y), f2b(f3.z), f2b(f3.w)};
        *(float4*)&As[0][ar * 32 + as0]     = ((const float4*)t16)[0];
        *(float4*)&As[0][ar * 32 + as0 + 8] = ((const float4*)t16)[1];
    } else {
#pragma unroll
        for (int i = 0; i < 2; i++) {
            int panel = wave * 2 + i;
            gl2lds16(&Ab16[(size_t)(m0 + panel * 16 + ldr) * ldk + kbase + ldc8],
                     &As[0][panel * 512]);
        }
    }
#pragma unroll
    for (int i = 0; i < 2; i++) {
        int panel = wave * 2 + i;
        gl2lds16(&Bb[(size_t)(n0 + panel * 16 + ldr) * ldk + kbase + ldc8],
                 &Bs[0][panel * 512]);
    }
    PIPE_BARRIER();

    for (int t = 0; t < nt; ++t) {
        const int cur = t & 1, nxt = cur ^ 1;
        const int kn = kbase + (t + 1) * 32;
        const bool pf = (t + 1 < nt);

        // ---- issue next tile's loads (hide under this tile's compute)
        float4 f0, f1, f2, f3;
        if (pf) {
            if (a_f32) {
                const float* p = Ab32 + (size_t)(m0 + ar) * ldk + kn + as0;
                f0 = *(const float4*)p;       f1 = *(const float4*)(p + 4);
                f2 = *(const float4*)(p + 8); f3 = *(const float4*)(p + 12);
            } else {
#pragma unroll
                for (int i = 0; i < 2; i++) {
                    int panel = wave * 2 + i;
                    gl2lds16(&Ab16[(size_t)(m0 + panel * 16 + ldr) * ldk + kn + ldc8],
                             &As[nxt][panel * 512]);
                }
            }
#pragma unroll
            for (int i = 0; i < 2; i++) {
                int panel = wave * 2 + i;
                gl2lds16(&Bb[(size_t)(n0 + panel * 16 + ldr) * ldk + kn + ldc8],
                         &Bs[nxt][panel * 512]);
            }
        }

        // ---- compute current tile
        bf16x8 af[4], bf[4];
#pragma unroll
        for (int i = 0; i < 4; i++) {
            af[i] = *(const bf16x8*)&As[cur][(wm * 64 + i * 16 + l16) * 32 + quad * 8];
            bf[i] = *(const bf16x8*)&Bs[cur][(wn * 64 + i * 16 + l16) * 32 + quad * 8];
        }
#pragma unroll
        for (int mb = 0; mb < 4; mb++)
#pragma unroll
            for (int nb = 0; nb < 4; nb++)
                acc[mb][nb] = __builtin_amdgcn_mfma_f32_16x16x32_bf16(
                    af[mb], bf[nb], acc[mb][nb], 0, 0, 0);

        // ---- finish staging next tile (fp32 A: cvt + LDS write, write-late)
        if (pf && a_f32) {
            alignas(16) unsigned short t16[16] = {
                f2b(f0.x), f2b(f0.y), f2b(f0.z), f2b(f0.w),
                f2b(f1.x), f2b(f1.y), f2b(f1.z), f2b(f1.w),
                f2b(f2.x), f2b(f2.y), f2b(f2.z), f2b(f2.w),
                f2b(f3.x), f2b(f3.y), f2b(f3.z), f2b(f3.w)};
            *(float4*)&As[nxt][ar * 32 + as0]     = ((const float4*)t16)[0];
            *(float4*)&As[nxt][ar * 32 + as0 + 8] = ((const float4*)t16)[1];
        }
        PIPE_BARRIER();
    }

    const size_t offC = (size_t)b * sCb + (size_t)ks * sCsplit;
#pragma unroll
    for (int mb = 0; mb < 4; mb++)
#pragma unroll
        for (int nb = 0; nb < 4; nb++)
#pragma unroll
            for (int r = 0; r < 4; r++) {
                int row = m0 + wm * 64 + mb * 16 + quad * 4 + r;
                int col = n0 + wn * 64 + nb * 16 + l16;
                size_t idx = offC + (writeT ? (size_t)col * ldc + row
                                            : (size_t)row * ldc + col);
                if (c_f32) ((float*)Cv)[idx] = acc[mb][nb][r];
                else ((unsigned short*)Cv)[idx] = f2b(acc[mb][nb][r]);
            }
}

// ---------------------------------------------------------------------------
// Sum 4 fp32 split-K partials (each 2,097,152 floats) -> bf16 G.
// 1024 blocks x 256 threads, 8 floats per thread.
// ---------------------------------------------------------------------------
__global__ __launch_bounds__(256) void reduceG_kernel(
    const float* __restrict__ P, unsigned short* __restrict__ G)
{
    const int i = blockIdx.x * 256 + threadIdx.x;   // 8 floats each
    const float4* p = (const float4*)P + (size_t)i * 2;
    const size_t st = 2097152 / 4;                  // float4 stride per split
    float4 a0 = p[0], a1 = p[1];
#pragma unroll
    for (int s = 1; s < 4; s++) {
        float4 b0 = p[(size_t)s * st], b1 = p[(size_t)s * st + 1];
        a0.x += b0.x; a0.y += b0.y; a0.z += b0.z; a0.w += b0.w;
        a1.x += b1.x; a1.y += b1.y; a1.z += b1.z; a1.w += b1.w;
    }
    alignas(16) unsigned short t[8] = {f2b(a0.x), f2b(a0.y), f2b(a0.z), f2b(a0.w),
                                       f2b(a1.x), f2b(a1.y), f2b(a1.z), f2b(a1.w)};
    ((float4*)G)[i] = *(const float4*)t;
}

// ---------------------------------------------------------------------------
// 64x64 dtype-flex GEMM (round-3, verified) for small shapes.
// ---------------------------------------------------------------------------
__global__ __launch_bounds__(256) void gemm64_kernel(
    const void* __restrict__ Av, int a_f32, size_t sAb, size_t sAh,
    const unsigned short* __restrict__ B, size_t sBb, size_t sBh,
    void* __restrict__ Cv, int c_f32, int writeT, int ldc, size_t sCb, size_t sCh,
    int K, int hshift, int hmask)
{
    __shared__ unsigned short As[64][40];
    __shared__ unsigned short Bs[64][40];

    const int tid  = threadIdx.x;
    const int wave = tid >> 6, lane = tid & 63;
    const int quad = lane >> 4, l16 = lane & 15;
    const int m0 = blockIdx.x * 64, n0 = blockIdx.y * 64;
    const int bz = blockIdx.z;
    const int b = bz >> hshift, h = bz & hmask;

    f32x4 acc[4];
#pragma unroll
    for (int i = 0; i < 4; i++) acc[i] = (f32x4){0.f, 0.f, 0.f, 0.f};

    const int ldrow = tid >> 2, ldseg = (tid & 3) * 8;
    const size_t offA = (size_t)b * sAb + (size_t)h * sAh;
    const size_t offB = (size_t)b * sBb + (size_t)h * sBh;

    for (int k0 = 0; k0 < K; k0 += 32) {
        __syncthreads();
        if (a_f32) {
            const float* p = (const float*)Av + offA + (size_t)(m0 + ldrow) * K + k0 + ldseg;
            float4 lo = *(const float4*)p, hi = *(const float4*)(p + 4);
            alignas(16) unsigned short t8[8] = {
                f2b(lo.x), f2b(lo.y), f2b(lo.z), f2b(lo.w),
                f2b(hi.x), f2b(hi.y), f2b(hi.z), f2b(hi.w)};
            *(float4*)&As[ldrow][ldseg] = *(const float4*)t8;
        } else {
            const unsigned short* p = (const unsigned short*)Av + offA +
                                      (size_t)(m0 + ldrow) * K + k0 + ldseg;
            *(float4*)&As[ldrow][ldseg] = *(const float4*)p;
        }
        {
            const unsigned short* p = B + offB + (size_t)(n0 + ldrow) * K + k0 + ldseg;
            *(float4*)&Bs[ldrow][ldseg] = *(const float4*)p;
        }
        __syncthreads();

        bf16x8 a = *(const bf16x8*)&As[wave * 16 + l16][quad * 8];
#pragma unroll
        for (int nb = 0; nb < 4; nb++) {
            bf16x8 bb = *(const bf16x8*)&Bs[nb * 16 + l16][quad * 8];
            acc[nb] = __builtin_amdgcn_mfma_f32_16x16x32_bf16(a, bb, acc[nb], 0, 0, 0);
        }
    }

    const size_t offC = (size_t)b * sCb + (size_t)h * sCh;
#pragma unroll
    for (int nb = 0; nb < 4; nb++)
#pragma unroll
        for (int r = 0; r < 4; r++) {
            int row = m0 + wave * 16 + quad * 4 + r;
            int col = n0 + nb * 16 + l16;
            size_t idx = offC + (writeT ? (size_t)col * ldc + row
                                        : (size_t)row * ldc + col);
            if (c_f32) ((float*)Cv)[idx] = acc[nb][r];
            else ((unsigned short*)Cv)[idx] = f2b(acc[nb][r]);
        }
}

// ---------------------------------------------------------------------------
// WvT[h][t][e] = bf16(Wv[h][e][t])
// ---------------------------------------------------------------------------
__global__ __launch_bounds__(256) void transpose_wv_kernel(
    const float* __restrict__ Wv, unsigned short* __restrict__ WvT)
{
    int i = blockIdx.x * 256 + threadIdx.x;
    int h = i >> 15, r = i & 32767;
    int t = r >> 6, e = i & 63;
    WvT[i] = f2b(Wv[(size_t)h * 32768 + (size_t)e * 512 + t]);
}

// ---------------------------------------------------------------------------
__global__ __launch_bounds__(64) void softmax_kernel(
    const float* __restrict__ S, unsigned short* __restrict__ w)
{
    const int bh = blockIdx.x;
    const int d  = threadIdx.x;
    const float* s = S + (size_t)bh * (HD * HD) + d * HD;
    float v[64];
    float m = -1e30f;
#pragma unroll
    for (int e = 0; e < 64; e++) { v[e] = s[e] * INV_SCALE; m = fmaxf(m, v[e]); }
    float sum = 0.f;
#pragma unroll
    for (int e = 0; e < 64; e++) { v[e] = __expf(v[e] - m); sum += v[e]; }
    float rinv = 1.0f / sum;
    unsigned short* o = w + (size_t)bh * (HD * HD) + d * HD;
#pragma unroll
    for (int e = 0; e < 64; e++) o[e] = f2b(v[e] * rinv);
}

// ---------------------------------------------------------------------------
extern "C" void kernel_launch(void* const* d_in, const int* in_sizes, int n_in,
                              void* d_out, int out_size, void* d_ws, size_t ws_size,
                              hipStream_t stream)
{
    const float* q  = (const float*)d_in[0];
    const float* k  = (const float*)d_in[1];
    const float* v  = (const float*)d_in[2];
    const float* Wq = (const float*)d_in[3];
    const float* Wk = (const float*)d_in[4];
    const float* Wv = (const float*)d_in[5];
    const float* Wo = (const float*)d_in[6];

    // workspace (element counts). Peak concurrent use:
    //   qT(32MB) + kT(32MB) + G(4MB) + P(32MB, aliases tmpT..free tail) = 100MB
    //   <= 102.7MB proven in round 2. P is dead after reduceG; tmpT/WkB/WoB/
    //   WvT/w/WveT/W2/S are all written after that point (single stream).
    unsigned short* qT   = (unsigned short*)d_ws;        // 16,777,216
    unsigned short* kT   = qT + 16777216;                // 16,777,216
    unsigned short* G    = kT + 16777216;                // 2,097,152
    unsigned short* tmpT = G + 2097152;                  // 2,097,152
    unsigned short* WkB  = tmpT + 2097152;               // 262,144
    unsigned short* WoB  = WkB + 262144;                 // 262,144
    unsigned short* WvT  = WoB + 262144;                 // 262,144
    unsigned short* w    = WvT + 262144;                 // 262,144
    unsigned short* WveT = w + 262144;                   // 2,097,152
    unsigned short* W2   = WveT + 2097152;               // 2,097,152
    float*          S    = (float*)(W2 + 2097152);       // 262,144 fp32
    float*          P    = (float*)tmpT;                 // 8,388,608 fp32 (split-K partials)

    // 0. q,k -> qT,kT (bf16, [b][t][c])
    transpose_qk_kernel<<<dim3(64, 8, 16), 256, 0, stream>>>(q, k, qT, kT);

    // 1. G[b][t][s] = sum_c qT[b][t][c] kT[b][s][c]   (K=4096, split-K x4)
    //    z = b*4 + ks; each block does K=1024 -> 512 blocks (2/CU).
    gemm128_kernel<<<dim3(4, 4, BS * 4), 256, 0, stream>>>(
        qT, 0, 16777216 / 8, kT, 2097152,
        P, 1, 0, 512, 262144, 4096, 1024, 2, 3, 2097152);
    reduceG_kernel<<<1024, 256, 0, stream>>>(P, G);

    // 0b. weight converts (after reduceG: their buffers alias P)
    cvt_kernel<<<128, 256, 0, stream>>>(Wk, WkB, 32768);
    cvt_kernel<<<128, 256, 0, stream>>>(Wo, WoB, 32768);
    transpose_wv_kernel<<<1024, 256, 0, stream>>>(Wv, WvT);

    // 2a. tmpT[b][he][t] = (G[b] * WkB^T)^T   (M=512 t, N=512 he, K=512 s)
    gemm128_kernel<<<dim3(4, 4, BS), 256, 0, stream>>>(
        G, 0, 262144, WkB, 0,
        tmpT, 0, 1, 512, 262144, 512, 512, 0, 0, 0);

    // 2b. S[b,h][d][e] = Wq[h] * tmpT[b,h]^T  (M=64, N=64, K=512)
    gemm64_kernel<<<dim3(1, 1, 64), 256, 0, stream>>>(
        Wq, 1, 0, 32768, tmpT, 262144, 32768,
        S, 1, 0, 64, 32768, 4096, 512, 3, 7);

    // 3. softmax
    softmax_kernel<<<64, 64, 0, stream>>>(S, w);

    // 4. WveT[b][t][h*64+d] = (w[b,h] * WvT[h]^T)^T   (M=64, N=512, K=64)
    gemm64_kernel<<<dim3(1, 8, 64), 256, 0, stream>>>(
        w, 0, 32768, 4096, WvT, 0, 32768,
        WveT, 0, 1, 512, 262144, 64, 64, 3, 7);

    // 5. W2[b][o][t] = WoB * WveT[b]^T   (M=512, N=512, K=512)
    gemm128_kernel<<<dim3(4, 4, BS), 256, 0, stream>>>(
        WoB, 0, 0, WveT, 262144,
        W2, 0, 0, 512, 262144, 512, 512, 0, 0, 0);

    // 6. out[b][c][o] = v[b] * W2[b]^T   (M=4096, N=512, K=512, A fp32)
    gemm128_kernel<<<dim3(32, 4, BS), 256, 0, stream>>>(
        v, 1, 2097152, W2, 262144,
        d_out, 1, 0, 512, 2097152, 512, 512, 0, 0, 0);
}